// Round 11
// baseline (232.293 us; speedup 1.0000x reference)
//
#include <hip/hip_runtime.h>

#define NFEAT 128
#define BSHIFT 9
#define BNODES 512            // dst nodes per bucket
#define NBMAX 256             // max buckets (N <= 131072)
#define BCAP 9216             // fixed packed capacity per bucket (mean 8163 + 11 sigma)
#define CHUNK 2048            // edges per partition block (r11: 8192->2048 for occupancy)

typedef __attribute__((ext_vector_type(8))) short bf16x8;
typedef __attribute__((ext_vector_type(4))) float f32x4;
typedef unsigned short u16;

__device__ inline u16 f2bf(float f) {            // RNE
    unsigned u = __float_as_uint(f);
    u += 0x7FFF + ((u >> 16) & 1);
    return (u16)(u >> 16);
}
__device__ inline float bf2f(u16 h) {
    return __uint_as_float((unsigned)h << 16);
}

// ---------------- single-pass partition into fixed-capacity buckets (+ out_deg) --------------
// packed[b*BCAP + slot] = ((dst & 511) << 17) | src ; cursor[b] counts edges in bucket b.
__global__ __launch_bounds__(256)
void partition_kernel(const int* __restrict__ src, const int* __restrict__ dst, int E,
                      int* __restrict__ cursor, int* __restrict__ packed,
                      int* __restrict__ out_deg, int NB) {
    __shared__ int cnt[NBMAX];
    for (int i = threadIdx.x; i < NB; i += 256) cnt[i] = 0;
    __syncthreads();
    int base = blockIdx.x * CHUNK;
    int end = min(base + CHUNK, E);
    for (int j = base + threadIdx.x; j < end; j += 256) {
        atomicAdd(&out_deg[src[j]], 1);
        atomicAdd(&cnt[dst[j] >> BSHIFT], 1);
    }
    __syncthreads();
    for (int i = threadIdx.x; i < NB; i += 256) {
        int c = cnt[i];
        cnt[i] = c ? (i * BCAP + atomicAdd(&cursor[i], c)) : 0;  // global run base
    }
    __syncthreads();
    for (int j = base + threadIdx.x; j < end; j += 256) {
        int d = dst[j];
        int b = d >> BSHIFT;
        int pos = atomicAdd(&cnt[b], 1);
        packed[pos] = ((d & (BNODES - 1)) << 17) | src[j];
    }
}

// ---------------- scan real bucket counts -> compact csr bases ----------------
__global__ void csr_scan_kernel(const int* __restrict__ cursor,
                                int* __restrict__ csr_base, int NB) {
    __shared__ int sa[256], sb[256];
    int tid = threadIdx.x;
    int v = (tid < NB) ? cursor[tid] : 0;
    sa[tid] = v;
    __syncthreads();
    int* s = sa; int* t = sb;
    for (int d = 1; d < 256; d <<= 1) {
        t[tid] = s[tid] + (tid >= d ? s[tid - d] : 0);
        __syncthreads();
        int* tmp = s; s = t; t = tmp;
    }
    if (tid < NB) csr_base[tid] = s[tid] - v;    // exclusive
    if (tid == 255) csr_base[NB] = s[255];       // = E
}

// ---------------- fat kernel: binfill (blocks 0..NB-1) || cast (NB..NB+nbc-1) || Wt (last) ---
__global__ __launch_bounds__(512)
void fill_cast_kernel(const int* __restrict__ packed, const int* __restrict__ cursor,
                      const int* __restrict__ csr_base,
                      int* __restrict__ row_start, float* __restrict__ inorm,
                      int* __restrict__ csr_src,
                      const float* __restrict__ x, const int* __restrict__ out_deg,
                      u16* __restrict__ xh, const float* __restrict__ W,
                      u16* __restrict__ Wt, int N, int E, int NB, int nbc) {
    int bid = blockIdx.x;
    int tid = threadIdx.x;

    if (bid < NB) {
        // ---- binfill: per-bucket node-sort of packed -> compact csr_src + row_start + inorm
        __shared__ int cnt[BNODES];
        __shared__ int sa[BNODES], sb[BNODES];
        int bkt = bid;
        int node0 = bkt << BSHIFT;
        int nn = min(BNODES, N - node0);
        int beg = bkt * BCAP;
        int ccnt = cursor[bkt];
        int csr0 = csr_base[bkt];

        cnt[tid] = 0;
        __syncthreads();
        for (int i = tid; i < ccnt; i += 512)
            atomicAdd(&cnt[packed[beg + i] >> 17], 1);
        __syncthreads();

        int v = cnt[tid];
        sa[tid] = v;
        __syncthreads();
        int* s = sa; int* t = sb;
        for (int d = 1; d < 512; d <<= 1) {
            t[tid] = s[tid] + (tid >= d ? s[tid - d] : 0);
            __syncthreads();
            int* tmp = s; s = t; t = tmp;
        }
        int excl = s[tid] - v;

        if (tid < nn) {
            row_start[node0 + tid] = csr0 + excl;
            inorm[node0 + tid] = rsqrtf((float)max(v, 1));
        }
        if (bkt == 0 && tid == 0) row_start[N] = E;
        __syncthreads();

        cnt[tid] = csr0 + excl;          // reuse as global cursor
        __syncthreads();
        for (int i = tid; i < ccnt; i += 512) {
            int p = packed[beg + i];
            int slot = atomicAdd(&cnt[p >> 17], 1);
            csr_src[slot] = p & 0x1FFFF;
        }
    } else if (bid < NB + nbc) {
        // ---- cast: xh[n][:] = bf16(x[n][:] * rsqrt(max(out_deg[n],1))), 128 rows/block
        int node0 = (bid - NB) << 7;
        for (int i = tid; i < 128 * 32; i += 512) {
            int r = i >> 5, f4 = i & 31;
            int n = node0 + r;
            if (n >= N) break;
            float sc = rsqrtf((float)max(out_deg[n], 1));
            float4 vv = *reinterpret_cast<const float4*>(&x[(size_t)n * NFEAT + f4 * 4]);
            ushort4 o;
            o.x = f2bf(vv.x * sc); o.y = f2bf(vv.y * sc);
            o.z = f2bf(vv.z * sc); o.w = f2bf(vv.w * sc);
            *reinterpret_cast<ushort4*>(&xh[(size_t)n * NFEAT + f4 * 4]) = o;
        }
    } else {
        // ---- Wt[col][k] = bf16(W[k][col])
        for (int i = tid; i < NFEAT * NFEAT; i += 512) {
            int col = i >> 7, k = i & 127;
            Wt[i] = f2bf(W[k * NFEAT + col]);
        }
    }
}

// ---------------- gather-aggregate (round-6 proven): half-wave per node, 8-wide ILP ----------
// Writes agg row (bf16, inorm-scaled) STRIDED at d_out + node*512B (payload first 256B).
__global__ __launch_bounds__(256)
void agg_bf16_kernel(const u16* __restrict__ xh, const int* __restrict__ csr_src,
                     const int* __restrict__ row_start, const float* __restrict__ inorm,
                     u16* __restrict__ aggh, int N) {
    int node = blockIdx.x * 8 + (threadIdx.x >> 5);
    if (node >= N) return;
    int lf = threadIdx.x & 31;
    int beg = row_start[node];
    int end = row_start[node + 1];
    const ushort4* xr = reinterpret_cast<const ushort4*>(xh);

    float4 acc = make_float4(0.f, 0.f, 0.f, 0.f);
    for (int i = beg; i < end; i += 8) {
        int s[8];
        float m[8];
        #pragma unroll
        for (int u = 0; u < 8; ++u) {          // phase 1: 8 independent index loads
            int j = i + u;
            bool ok = (j < end);
            s[u] = ok ? csr_src[j] : 0;
            m[u] = ok ? 1.f : 0.f;
        }
        ushort4 v[8];
        #pragma unroll
        for (int u = 0; u < 8; ++u)            // phase 2: 8 independent row gathers
            v[u] = xr[(size_t)s[u] * 32 + lf];
        #pragma unroll
        for (int u = 0; u < 8; ++u) {          // phase 3: masked accumulate
            acc.x = fmaf(m[u], bf2f(v[u].x), acc.x);
            acc.y = fmaf(m[u], bf2f(v[u].y), acc.y);
            acc.z = fmaf(m[u], bf2f(v[u].z), acc.z);
            acc.w = fmaf(m[u], bf2f(v[u].w), acc.w);
        }
    }
    float in_n = inorm[node];
    ushort4 o;
    o.x = f2bf(acc.x * in_n);
    o.y = f2bf(acc.y * in_n);
    o.z = f2bf(acc.z * in_n);
    o.w = f2bf(acc.w * in_n);
    *reinterpret_cast<ushort4*>(aggh + (size_t)node * 256 + lf * 4) = o;
}

// ---------------- MFMA projection (round-5 proven): out = aggh @ W + b, in-place -----------
__global__ __launch_bounds__(256)
void mm_mfma_kernel(const u16* __restrict__ aggh, float* outp,
                    const u16* __restrict__ Wt, const float* __restrict__ b, int N) {
    __shared__ u16 Al[NFEAT * NFEAT];   // 32 KiB
    __shared__ u16 Bl[NFEAT * NFEAT];   // 32 KiB  (Wt: [col][k])
    int tid = threadIdx.x;
    int r0 = blockIdx.x * 128;

    for (int c = tid; c < 2048; c += 256) {
        int col = c >> 4, sub = c & 15;
        int slot = sub ^ (col & 7);
        *reinterpret_cast<uint4*>(reinterpret_cast<char*>(Bl) + col * 256 + slot * 16) =
            *reinterpret_cast<const uint4*>(reinterpret_cast<const char*>(Wt) + c * 16);
    }
    for (int c = tid; c < 2048; c += 256) {
        int row = c >> 4, sub = c & 15;
        int grow = min(r0 + row, N - 1);
        int slot = sub ^ (row & 7);
        *reinterpret_cast<uint4*>(reinterpret_cast<char*>(Al) + row * 256 + slot * 16) =
            *reinterpret_cast<const uint4*>(reinterpret_cast<const char*>(aggh) +
                                            (size_t)grow * 512 + sub * 16);
    }
    __syncthreads();

    int lane = tid & 63;
    int wave = tid >> 6;
    int wr = wave >> 1, wc = wave & 1;
    int lrow = lane & 15, hi = lane >> 4;

    f32x4 zero = {0.f, 0.f, 0.f, 0.f};
    f32x4 acc[4][4];
    #pragma unroll
    for (int rt = 0; rt < 4; ++rt)
        #pragma unroll
        for (int ct = 0; ct < 4; ++ct) acc[rt][ct] = zero;

    #pragma unroll
    for (int ks = 0; ks < 4; ++ks) {
        int chunk = ks * 4 + hi;
        bf16x8 af[4], bfr[4];
        #pragma unroll
        for (int rt = 0; rt < 4; ++rt) {
            int row = wr * 64 + rt * 16 + lrow;
            af[rt] = *reinterpret_cast<bf16x8*>(reinterpret_cast<char*>(Al) + row * 256 +
                                                ((chunk ^ (row & 7)) * 16));
        }
        #pragma unroll
        for (int ct = 0; ct < 4; ++ct) {
            int col = wc * 64 + ct * 16 + lrow;
            bfr[ct] = *reinterpret_cast<bf16x8*>(reinterpret_cast<char*>(Bl) + col * 256 +
                                                 ((chunk ^ (col & 7)) * 16));
        }
        #pragma unroll
        for (int rt = 0; rt < 4; ++rt)
            #pragma unroll
            for (int ct = 0; ct < 4; ++ct)
                acc[rt][ct] = __builtin_amdgcn_mfma_f32_16x16x32_bf16(af[rt], bfr[ct],
                                                                     acc[rt][ct], 0, 0, 0);
    }

    #pragma unroll
    for (int ct = 0; ct < 4; ++ct) {
        int col = wc * 64 + ct * 16 + lrow;
        float bias = b[col];
        #pragma unroll
        for (int rt = 0; rt < 4; ++rt) {
            int rbase = r0 + wr * 64 + rt * 16 + hi * 4;
            #pragma unroll
            for (int q = 0; q < 4; ++q) {
                int row = rbase + q;
                if (row < N) outp[(size_t)row * NFEAT + col] = acc[rt][ct][q] + bias;
            }
        }
    }
}

extern "C" void kernel_launch(void* const* d_in, const int* in_sizes, int n_in,
                              void* d_out, int out_size, void* d_ws, size_t ws_size,
                              hipStream_t stream) {
    const float* x   = (const float*)d_in[0];
    const int*   src = (const int*)d_in[1];
    const int*   dst = (const int*)d_in[2];
    const float* W   = (const float*)d_in[3];
    const float* b   = (const float*)d_in[4];

    const int N = in_sizes[0] / NFEAT;   // 100000
    const int E = in_sizes[1];           // 1600000
    float* out = (float*)d_out;

    const int NB = (N + BNODES - 1) >> BSHIFT;   // 196

    // ws layout (ints unless noted):
    // [out_deg N][cursor NBMAX]  <- zeroed together
    // [csr_base NBMAX+1][row_start N+1][inorm N f32][csr_src E][Wt 16384 bf16][xh N*128 bf16]
    int*   out_deg   = (int*)d_ws;
    int*   cursor    = out_deg + N;
    int*   csr_base  = cursor + NBMAX;
    int*   row_start = csr_base + (NBMAX + 1);
    float* inorm     = (float*)(row_start + (N + 1));
    int*   csr_src   = (int*)(inorm + N);
    u16*   Wt        = (u16*)(csr_src + E);
    u16*   xh        = Wt + NFEAT * NFEAT;

    // fixed-capacity packed buckets live in d_out (NB*BCAP ints = 7.2MB); dead before agg.
    int* packed = (int*)d_out;

    hipMemsetAsync(d_ws, 0, (size_t)(N + NBMAX) * sizeof(int), stream);

    int nchunk = (E + CHUNK - 1) / CHUNK;        // 782
    partition_kernel<<<nchunk, 256, 0, stream>>>(src, dst, E, cursor, packed, out_deg, NB);
    csr_scan_kernel<<<1, 256, 0, stream>>>(cursor, csr_base, NB);

    int nbc = (N + 127) >> 7;                    // 782 cast blocks
    fill_cast_kernel<<<NB + nbc + 1, 512, 0, stream>>>(packed, cursor, csr_base,
                                                       row_start, inorm, csr_src,
                                                       x, out_deg, xh, W, Wt, N, E, NB, nbc);

    u16* aggh = (u16*)d_out;                     // strided: node i payload at byte i*512
    agg_bf16_kernel<<<(N + 7) / 8, 256, 0, stream>>>(xh, csr_src, row_start, inorm, aggh, N);

    mm_mfma_kernel<<<(N + 127) / 128, 256, 0, stream>>>(aggh, out, Wt, b, N);
}

// Round 12
// 227.482 us; speedup vs baseline: 1.0212x; 1.0212x over previous
//
#include <hip/hip_runtime.h>

#define NFEAT 128
#define BSHIFT 9
#define BNODES 512            // dst nodes per bucket
#define NBMAX 256             // max buckets (N <= 131072)
#define BCAP 9216             // fixed packed capacity per bucket (mean 8163 + 11 sigma)
#define CHUNK 4096            // edges per partition block

typedef __attribute__((ext_vector_type(8))) short bf16x8;
typedef __attribute__((ext_vector_type(4))) float f32x4;
typedef unsigned short u16;

__device__ inline u16 f2bf(float f) {            // RNE
    unsigned u = __float_as_uint(f);
    u += 0x7FFF + ((u >> 16) & 1);
    return (u16)(u >> 16);
}
__device__ inline float bf2f(u16 h) {
    return __uint_as_float((unsigned)h << 16);
}

// ---------------- out-degree histogram (isolated; fire-and-forget atomics) ----------------
__global__ __launch_bounds__(256)
void deg_kernel(const int* __restrict__ src, int E, int* __restrict__ out_deg) {
    int stride = gridDim.x * 256;
    for (int i = blockIdx.x * 256 + threadIdx.x; i < E; i += stride)
        atomicAdd(&out_deg[src[i]], 1);
}

// ---------------- partition v3: LDS counting sort per chunk + coalesced flush ----------------
// packed[b*BCAP + slot] = ((dst & 511) << 17) | src ; cursor[b] counts edges in bucket b.
__global__ __launch_bounds__(512)
void partition_kernel(const int* __restrict__ src, const int* __restrict__ dst, int E,
                      int* __restrict__ cursor, int* __restrict__ packed, int NB) {
    __shared__ int cnt[NBMAX];            // hist -> local cursor
    __shared__ int loff[NBMAX];           // local exclusive offsets
    __shared__ int gbase[NBMAX];          // global run base per bucket
    __shared__ int sa[NBMAX], sb[NBMAX];
    __shared__ int sortv[CHUNK];          // 16 KiB sorted packed values
    __shared__ u16 sortb[CHUNK];          // 8 KiB bucket id per slot

    int tid = threadIdx.x;
    if (tid < NBMAX) cnt[tid] = 0;
    __syncthreads();

    int base = blockIdx.x * CHUNK;
    int endj = min(base + CHUNK, E);
    int ccnt = endj - base;

    for (int j = base + tid; j < endj; j += 512)
        atomicAdd(&cnt[dst[j] >> BSHIFT], 1);
    __syncthreads();

    int v = (tid < NBMAX) ? cnt[tid] : 0;
    if (tid < NBMAX) sa[tid] = v;
    __syncthreads();
    int* s = sa; int* t = sb;
    for (int d = 1; d < NBMAX; d <<= 1) {
        if (tid < NBMAX) t[tid] = s[tid] + (tid >= d ? s[tid - d] : 0);
        __syncthreads();
        int* tmp = s; s = t; t = tmp;
    }
    if (tid < NBMAX) {
        int excl = s[tid] - v;
        loff[tid] = excl;
        cnt[tid] = excl;                               // local placement cursor
        gbase[tid] = v ? (tid * BCAP + atomicAdd(&cursor[tid], v)) : 0;
    }
    __syncthreads();

    for (int j = base + tid; j < endj; j += 512) {
        int d_ = dst[j];
        int bkt = d_ >> BSHIFT;
        int pos = atomicAdd(&cnt[bkt], 1);
        sortv[pos] = ((d_ & (BNODES - 1)) << 17) | src[j];
        sortb[pos] = (u16)bkt;
    }
    __syncthreads();

    // coalesced flush: consecutive p (mostly same bucket run) -> consecutive global addresses
    for (int p = tid; p < ccnt; p += 512) {
        int bkt = sortb[p];
        packed[gbase[bkt] + (p - loff[bkt])] = sortv[p];
    }
}

// ---------------- scan real bucket counts -> compact csr bases ----------------
__global__ void csr_scan_kernel(const int* __restrict__ cursor,
                                int* __restrict__ csr_base, int NB) {
    __shared__ int sa[256], sb[256];
    int tid = threadIdx.x;
    int v = (tid < NB) ? cursor[tid] : 0;
    sa[tid] = v;
    __syncthreads();
    int* s = sa; int* t = sb;
    for (int d = 1; d < 256; d <<= 1) {
        t[tid] = s[tid] + (tid >= d ? s[tid - d] : 0);
        __syncthreads();
        int* tmp = s; s = t; t = tmp;
    }
    if (tid < NB) csr_base[tid] = s[tid] - v;    // exclusive
    if (tid == 255) csr_base[NB] = s[255];       // = E
}

// ---------------- fat kernel: binfill (blocks 0..NB-1) || cast (NB..NB+nbc-1) || Wt (last) ---
__global__ __launch_bounds__(512)
void fill_cast_kernel(const int* __restrict__ packed, const int* __restrict__ cursor,
                      const int* __restrict__ csr_base,
                      int* __restrict__ row_start, float* __restrict__ inorm,
                      int* __restrict__ csr_src,
                      const float* __restrict__ x, const int* __restrict__ out_deg,
                      u16* __restrict__ xh, const float* __restrict__ W,
                      u16* __restrict__ Wt, int N, int E, int NB, int nbc) {
    int bid = blockIdx.x;
    int tid = threadIdx.x;

    if (bid < NB) {
        // ---- binfill: per-bucket node-sort of packed -> compact csr_src + row_start + inorm
        __shared__ int cnt[BNODES];
        __shared__ int sa[BNODES], sb[BNODES];
        int bkt = bid;
        int node0 = bkt << BSHIFT;
        int nn = min(BNODES, N - node0);
        int beg = bkt * BCAP;
        int ccnt = cursor[bkt];
        int csr0 = csr_base[bkt];

        cnt[tid] = 0;
        __syncthreads();
        for (int i = tid; i < ccnt; i += 512)
            atomicAdd(&cnt[packed[beg + i] >> 17], 1);
        __syncthreads();

        int v = cnt[tid];
        sa[tid] = v;
        __syncthreads();
        int* s = sa; int* t = sb;
        for (int d = 1; d < 512; d <<= 1) {
            t[tid] = s[tid] + (tid >= d ? s[tid - d] : 0);
            __syncthreads();
            int* tmp = s; s = t; t = tmp;
        }
        int excl = s[tid] - v;

        if (tid < nn) {
            row_start[node0 + tid] = csr0 + excl;
            inorm[node0 + tid] = rsqrtf((float)max(v, 1));
        }
        if (bkt == 0 && tid == 0) row_start[N] = E;
        __syncthreads();

        cnt[tid] = csr0 + excl;          // reuse as global cursor
        __syncthreads();
        for (int i = tid; i < ccnt; i += 512) {
            int p = packed[beg + i];
            int slot = atomicAdd(&cnt[p >> 17], 1);
            csr_src[slot] = p & 0x1FFFF;
        }
    } else if (bid < NB + nbc) {
        // ---- cast: xh[n][:] = bf16(x[n][:] * rsqrt(max(out_deg[n],1))), 128 rows/block
        int node0 = (bid - NB) << 7;
        for (int i = tid; i < 128 * 32; i += 512) {
            int r = i >> 5, f4 = i & 31;
            int n = node0 + r;
            if (n >= N) break;
            float sc = rsqrtf((float)max(out_deg[n], 1));
            float4 vv = *reinterpret_cast<const float4*>(&x[(size_t)n * NFEAT + f4 * 4]);
            ushort4 o;
            o.x = f2bf(vv.x * sc); o.y = f2bf(vv.y * sc);
            o.z = f2bf(vv.z * sc); o.w = f2bf(vv.w * sc);
            *reinterpret_cast<ushort4*>(&xh[(size_t)n * NFEAT + f4 * 4]) = o;
        }
    } else {
        // ---- Wt[col][k] = bf16(W[k][col])
        for (int i = tid; i < NFEAT * NFEAT; i += 512) {
            int col = i >> 7, k = i & 127;
            Wt[i] = f2bf(W[k * NFEAT + col]);
        }
    }
}

// ---------------- gather-aggregate (round-6 proven): half-wave per node, 8-wide ILP ----------
// Writes agg row (bf16, inorm-scaled) STRIDED at d_out + node*512B (payload first 256B).
__global__ __launch_bounds__(256)
void agg_bf16_kernel(const u16* __restrict__ xh, const int* __restrict__ csr_src,
                     const int* __restrict__ row_start, const float* __restrict__ inorm,
                     u16* __restrict__ aggh, int N) {
    int node = blockIdx.x * 8 + (threadIdx.x >> 5);
    if (node >= N) return;
    int lf = threadIdx.x & 31;
    int beg = row_start[node];
    int end = row_start[node + 1];
    const ushort4* xr = reinterpret_cast<const ushort4*>(xh);

    float4 acc = make_float4(0.f, 0.f, 0.f, 0.f);
    for (int i = beg; i < end; i += 8) {
        int s[8];
        float m[8];
        #pragma unroll
        for (int u = 0; u < 8; ++u) {          // phase 1: 8 independent index loads
            int j = i + u;
            bool ok = (j < end);
            s[u] = ok ? csr_src[j] : 0;
            m[u] = ok ? 1.f : 0.f;
        }
        ushort4 v[8];
        #pragma unroll
        for (int u = 0; u < 8; ++u)            // phase 2: 8 independent row gathers
            v[u] = xr[(size_t)s[u] * 32 + lf];
        #pragma unroll
        for (int u = 0; u < 8; ++u) {          // phase 3: masked accumulate
            acc.x = fmaf(m[u], bf2f(v[u].x), acc.x);
            acc.y = fmaf(m[u], bf2f(v[u].y), acc.y);
            acc.z = fmaf(m[u], bf2f(v[u].z), acc.z);
            acc.w = fmaf(m[u], bf2f(v[u].w), acc.w);
        }
    }
    float in_n = inorm[node];
    ushort4 o;
    o.x = f2bf(acc.x * in_n);
    o.y = f2bf(acc.y * in_n);
    o.z = f2bf(acc.z * in_n);
    o.w = f2bf(acc.w * in_n);
    *reinterpret_cast<ushort4*>(aggh + (size_t)node * 256 + lf * 4) = o;
}

// ---------------- MFMA projection (round-5 proven): out = aggh @ W + b, in-place -----------
__global__ __launch_bounds__(256)
void mm_mfma_kernel(const u16* __restrict__ aggh, float* outp,
                    const u16* __restrict__ Wt, const float* __restrict__ b, int N) {
    __shared__ u16 Al[NFEAT * NFEAT];   // 32 KiB
    __shared__ u16 Bl[NFEAT * NFEAT];   // 32 KiB  (Wt: [col][k])
    int tid = threadIdx.x;
    int r0 = blockIdx.x * 128;

    for (int c = tid; c < 2048; c += 256) {
        int col = c >> 4, sub = c & 15;
        int slot = sub ^ (col & 7);
        *reinterpret_cast<uint4*>(reinterpret_cast<char*>(Bl) + col * 256 + slot * 16) =
            *reinterpret_cast<const uint4*>(reinterpret_cast<const char*>(Wt) + c * 16);
    }
    for (int c = tid; c < 2048; c += 256) {
        int row = c >> 4, sub = c & 15;
        int grow = min(r0 + row, N - 1);
        int slot = sub ^ (row & 7);
        *reinterpret_cast<uint4*>(reinterpret_cast<char*>(Al) + row * 256 + slot * 16) =
            *reinterpret_cast<const uint4*>(reinterpret_cast<const char*>(aggh) +
                                            (size_t)grow * 512 + sub * 16);
    }
    __syncthreads();

    int lane = tid & 63;
    int wave = tid >> 6;
    int wr = wave >> 1, wc = wave & 1;
    int lrow = lane & 15, hi = lane >> 4;

    f32x4 zero = {0.f, 0.f, 0.f, 0.f};
    f32x4 acc[4][4];
    #pragma unroll
    for (int rt = 0; rt < 4; ++rt)
        #pragma unroll
        for (int ct = 0; ct < 4; ++ct) acc[rt][ct] = zero;

    #pragma unroll
    for (int ks = 0; ks < 4; ++ks) {
        int chunk = ks * 4 + hi;
        bf16x8 af[4], bfr[4];
        #pragma unroll
        for (int rt = 0; rt < 4; ++rt) {
            int row = wr * 64 + rt * 16 + lrow;
            af[rt] = *reinterpret_cast<bf16x8*>(reinterpret_cast<char*>(Al) + row * 256 +
                                                ((chunk ^ (row & 7)) * 16));
        }
        #pragma unroll
        for (int ct = 0; ct < 4; ++ct) {
            int col = wc * 64 + ct * 16 + lrow;
            bfr[ct] = *reinterpret_cast<bf16x8*>(reinterpret_cast<char*>(Bl) + col * 256 +
                                                 ((chunk ^ (col & 7)) * 16));
        }
        #pragma unroll
        for (int rt = 0; rt < 4; ++rt)
            #pragma unroll
            for (int ct = 0; ct < 4; ++ct)
                acc[rt][ct] = __builtin_amdgcn_mfma_f32_16x16x32_bf16(af[rt], bfr[ct],
                                                                     acc[rt][ct], 0, 0, 0);
    }

    #pragma unroll
    for (int ct = 0; ct < 4; ++ct) {
        int col = wc * 64 + ct * 16 + lrow;
        float bias = b[col];
        #pragma unroll
        for (int rt = 0; rt < 4; ++rt) {
            int rbase = r0 + wr * 64 + rt * 16 + hi * 4;
            #pragma unroll
            for (int q = 0; q < 4; ++q) {
                int row = rbase + q;
                if (row < N) outp[(size_t)row * NFEAT + col] = acc[rt][ct][q] + bias;
            }
        }
    }
}

extern "C" void kernel_launch(void* const* d_in, const int* in_sizes, int n_in,
                              void* d_out, int out_size, void* d_ws, size_t ws_size,
                              hipStream_t stream) {
    const float* x   = (const float*)d_in[0];
    const int*   src = (const int*)d_in[1];
    const int*   dst = (const int*)d_in[2];
    const float* W   = (const float*)d_in[3];
    const float* b   = (const float*)d_in[4];

    const int N = in_sizes[0] / NFEAT;   // 100000
    const int E = in_sizes[1];           // 1600000
    float* out = (float*)d_out;

    const int NB = (N + BNODES - 1) >> BSHIFT;   // 196

    // ws layout (ints unless noted):
    // [out_deg N][cursor NBMAX]  <- zeroed together
    // [csr_base NBMAX+1][row_start N+1][inorm N f32][csr_src E][Wt 16384 bf16][xh N*128 bf16]
    int*   out_deg   = (int*)d_ws;
    int*   cursor    = out_deg + N;
    int*   csr_base  = cursor + NBMAX;
    int*   row_start = csr_base + (NBMAX + 1);
    float* inorm     = (float*)(row_start + (N + 1));
    int*   csr_src   = (int*)(inorm + N);
    u16*   Wt        = (u16*)(csr_src + E);
    u16*   xh        = Wt + NFEAT * NFEAT;

    // fixed-capacity packed buckets live in d_out (NB*BCAP ints = 7.2MB); dead before agg.
    int* packed = (int*)d_out;

    hipMemsetAsync(d_ws, 0, (size_t)(N + NBMAX) * sizeof(int), stream);

    deg_kernel<<<2048, 256, 0, stream>>>(src, E, out_deg);

    int nchunk = (E + CHUNK - 1) / CHUNK;        // 391
    partition_kernel<<<nchunk, 512, 0, stream>>>(src, dst, E, cursor, packed, NB);
    csr_scan_kernel<<<1, 256, 0, stream>>>(cursor, csr_base, NB);

    int nbc = (N + 127) >> 7;                    // 782 cast blocks
    fill_cast_kernel<<<NB + nbc + 1, 512, 0, stream>>>(packed, cursor, csr_base,
                                                       row_start, inorm, csr_src,
                                                       x, out_deg, xh, W, Wt, N, E, NB, nbc);

    u16* aggh = (u16*)d_out;                     // strided: node i payload at byte i*512
    agg_bf16_kernel<<<(N + 7) / 8, 256, 0, stream>>>(xh, csr_src, row_start, inorm, aggh, N);

    mm_mfma_kernel<<<(N + 127) / 128, 256, 0, stream>>>(aggh, out, Wt, b, N);
}

// Round 13
// 215.983 us; speedup vs baseline: 1.0755x; 1.0532x over previous
//
#include <hip/hip_runtime.h>

#define NFEAT 128
#define BSHIFT 9
#define BNODES 512            // dst nodes per bucket
#define NBMAX 256             // max buckets (N <= 131072)
#define BCAP 9216             // fixed packed capacity per bucket (mean 8163 + 11 sigma)
#define CHUNK 4096            // edges per partition block

typedef __attribute__((ext_vector_type(8))) short bf16x8;
typedef __attribute__((ext_vector_type(4))) float f32x4;
typedef unsigned short u16;

__device__ inline u16 f2bf(float f) {            // RNE
    unsigned u = __float_as_uint(f);
    u += 0x7FFF + ((u >> 16) & 1);
    return (u16)(u >> 16);
}
__device__ inline float bf2f(u16 h) {
    return __uint_as_float((unsigned)h << 16);
}

// ---------------- partition v3 + fused out-degree histogram ----------------
// packed[b*BCAP + slot] = ((dst & 511) << 17) | src ; cursor[b] counts edges in bucket b.
__global__ __launch_bounds__(512)
void partition_kernel(const int* __restrict__ src, const int* __restrict__ dst, int E,
                      int* __restrict__ cursor, int* __restrict__ packed,
                      int* __restrict__ out_deg, int NB) {
    __shared__ int cnt[NBMAX];            // hist -> local cursor
    __shared__ int loff[NBMAX];           // local exclusive offsets
    __shared__ int gbase[NBMAX];          // global run base per bucket
    __shared__ int sa[NBMAX], sb[NBMAX];
    __shared__ int sortv[CHUNK];          // 16 KiB sorted packed values
    __shared__ u16 sortb[CHUNK];          // 8 KiB bucket id per slot

    int tid = threadIdx.x;
    if (tid < NBMAX) cnt[tid] = 0;
    __syncthreads();

    int base = blockIdx.x * CHUNK;
    int endj = min(base + CHUNK, E);
    int ccnt = endj - base;

    for (int j = base + tid; j < endj; j += 512) {
        atomicAdd(&out_deg[src[j]], 1);            // fused deg histogram (fire-and-forget)
        atomicAdd(&cnt[dst[j] >> BSHIFT], 1);
    }
    __syncthreads();

    int v = (tid < NBMAX) ? cnt[tid] : 0;
    if (tid < NBMAX) sa[tid] = v;
    __syncthreads();
    int* s = sa; int* t = sb;
    for (int d = 1; d < NBMAX; d <<= 1) {
        if (tid < NBMAX) t[tid] = s[tid] + (tid >= d ? s[tid - d] : 0);
        __syncthreads();
        int* tmp = s; s = t; t = tmp;
    }
    if (tid < NBMAX) {
        int excl = s[tid] - v;
        loff[tid] = excl;
        cnt[tid] = excl;                               // local placement cursor
        gbase[tid] = v ? (tid * BCAP + atomicAdd(&cursor[tid], v)) : 0;
    }
    __syncthreads();

    for (int j = base + tid; j < endj; j += 512) {
        int d_ = dst[j];
        int bkt = d_ >> BSHIFT;
        int pos = atomicAdd(&cnt[bkt], 1);
        sortv[pos] = ((d_ & (BNODES - 1)) << 17) | src[j];
        sortb[pos] = (u16)bkt;
    }
    __syncthreads();

    // coalesced flush: consecutive p (mostly same bucket run) -> consecutive global addresses
    for (int p = tid; p < ccnt; p += 512) {
        int bkt = sortb[p];
        packed[gbase[bkt] + (p - loff[bkt])] = sortv[p];
    }
}

// ---------------- fat kernel: binfill (blocks 0..NB-1) || cast (NB..NB+nbc-1) || Wt (last) ---
__global__ __launch_bounds__(512)
void fill_cast_kernel(const int* __restrict__ packed, const int* __restrict__ cursor,
                      int* __restrict__ row_start, float* __restrict__ inorm,
                      int* __restrict__ csr_src,
                      const float* __restrict__ x, const int* __restrict__ out_deg,
                      u16* __restrict__ xh, const float* __restrict__ W,
                      u16* __restrict__ Wt, int N, int E, int NB, int nbc) {
    int bid = blockIdx.x;
    int tid = threadIdx.x;

    if (bid < NB) {
        // ---- binfill: per-bucket node-sort of packed -> compact csr_src + row_start + inorm
        __shared__ int cnt[BNODES];
        __shared__ int sa[BNODES], sb[BNODES];
        __shared__ int ca[256], cb[256];
        int bkt = bid;
        int node0 = bkt << BSHIFT;
        int nn = min(BNODES, N - node0);
        int beg = bkt * BCAP;
        int ccnt = cursor[bkt];

        // in-block csr_base: inclusive scan of cursor[0..NB) (196 ints)
        if (tid < 256) ca[tid] = (tid < NB) ? cursor[tid] : 0;
        __syncthreads();
        int* p = ca; int* q = cb;
        for (int d = 1; d < 256; d <<= 1) {
            if (tid < 256) q[tid] = p[tid] + (tid >= d ? p[tid - d] : 0);
            __syncthreads();
            int* tmp = p; p = q; q = tmp;
        }
        int csr0 = (bkt > 0) ? p[bkt - 1] : 0;
        if (bkt == 0 && tid == 0) row_start[N] = p[NB - 1];   // = E

        cnt[tid] = 0;
        __syncthreads();
        for (int i = tid; i < ccnt; i += 512)
            atomicAdd(&cnt[packed[beg + i] >> 17], 1);
        __syncthreads();

        int v = cnt[tid];
        sa[tid] = v;
        __syncthreads();
        int* s = sa; int* t = sb;
        for (int d = 1; d < 512; d <<= 1) {
            t[tid] = s[tid] + (tid >= d ? s[tid - d] : 0);
            __syncthreads();
            int* tmp = s; s = t; t = tmp;
        }
        int excl = s[tid] - v;

        if (tid < nn) {
            row_start[node0 + tid] = csr0 + excl;
            inorm[node0 + tid] = rsqrtf((float)max(v, 1));
        }
        __syncthreads();

        cnt[tid] = csr0 + excl;          // reuse as global cursor
        __syncthreads();
        for (int i = tid; i < ccnt; i += 512) {
            int pk = packed[beg + i];
            int slot = atomicAdd(&cnt[pk >> 17], 1);
            csr_src[slot] = pk & 0x1FFFF;
        }
    } else if (bid < NB + nbc) {
        // ---- cast: xh[n][:] = bf16(x[n][:] * rsqrt(max(out_deg[n],1))), 128 rows/block
        int node0 = (bid - NB) << 7;
        for (int i = tid; i < 128 * 32; i += 512) {
            int r = i >> 5, f4 = i & 31;
            int n = node0 + r;
            if (n >= N) break;
            float sc = rsqrtf((float)max(out_deg[n], 1));
            float4 vv = *reinterpret_cast<const float4*>(&x[(size_t)n * NFEAT + f4 * 4]);
            ushort4 o;
            o.x = f2bf(vv.x * sc); o.y = f2bf(vv.y * sc);
            o.z = f2bf(vv.z * sc); o.w = f2bf(vv.w * sc);
            *reinterpret_cast<ushort4*>(&xh[(size_t)n * NFEAT + f4 * 4]) = o;
        }
    } else {
        // ---- Wt[col][k] = bf16(W[k][col])
        for (int i = tid; i < NFEAT * NFEAT; i += 512) {
            int col = i >> 7, k = i & 127;
            Wt[i] = f2bf(W[k * NFEAT + col]);
        }
    }
}

// ---------------- gather-aggregate (round-6 proven): half-wave per node, 8-wide ILP ----------
// Writes agg row (bf16, inorm-scaled) STRIDED at d_out + node*512B (payload first 256B).
__global__ __launch_bounds__(256)
void agg_bf16_kernel(const u16* __restrict__ xh, const int* __restrict__ csr_src,
                     const int* __restrict__ row_start, const float* __restrict__ inorm,
                     u16* __restrict__ aggh, int N) {
    int node = blockIdx.x * 8 + (threadIdx.x >> 5);
    if (node >= N) return;
    int lf = threadIdx.x & 31;
    int beg = row_start[node];
    int end = row_start[node + 1];
    const ushort4* xr = reinterpret_cast<const ushort4*>(xh);

    float4 acc = make_float4(0.f, 0.f, 0.f, 0.f);
    for (int i = beg; i < end; i += 8) {
        int s[8];
        float m[8];
        #pragma unroll
        for (int u = 0; u < 8; ++u) {          // phase 1: 8 independent index loads
            int j = i + u;
            bool ok = (j < end);
            s[u] = ok ? csr_src[j] : 0;
            m[u] = ok ? 1.f : 0.f;
        }
        ushort4 v[8];
        #pragma unroll
        for (int u = 0; u < 8; ++u)            // phase 2: 8 independent row gathers
            v[u] = xr[(size_t)s[u] * 32 + lf];
        #pragma unroll
        for (int u = 0; u < 8; ++u) {          // phase 3: masked accumulate
            acc.x = fmaf(m[u], bf2f(v[u].x), acc.x);
            acc.y = fmaf(m[u], bf2f(v[u].y), acc.y);
            acc.z = fmaf(m[u], bf2f(v[u].z), acc.z);
            acc.w = fmaf(m[u], bf2f(v[u].w), acc.w);
        }
    }
    float in_n = inorm[node];
    ushort4 o;
    o.x = f2bf(acc.x * in_n);
    o.y = f2bf(acc.y * in_n);
    o.z = f2bf(acc.z * in_n);
    o.w = f2bf(acc.w * in_n);
    *reinterpret_cast<ushort4*>(aggh + (size_t)node * 256 + lf * 4) = o;
}

// ---------------- MFMA projection (round-5 proven): out = aggh @ W + b, in-place -----------
__global__ __launch_bounds__(256)
void mm_mfma_kernel(const u16* __restrict__ aggh, float* outp,
                    const u16* __restrict__ Wt, const float* __restrict__ b, int N) {
    __shared__ u16 Al[NFEAT * NFEAT];   // 32 KiB
    __shared__ u16 Bl[NFEAT * NFEAT];   // 32 KiB  (Wt: [col][k])
    int tid = threadIdx.x;
    int r0 = blockIdx.x * 128;

    for (int c = tid; c < 2048; c += 256) {
        int col = c >> 4, sub = c & 15;
        int slot = sub ^ (col & 7);
        *reinterpret_cast<uint4*>(reinterpret_cast<char*>(Bl) + col * 256 + slot * 16) =
            *reinterpret_cast<const uint4*>(reinterpret_cast<const char*>(Wt) + c * 16);
    }
    for (int c = tid; c < 2048; c += 256) {
        int row = c >> 4, sub = c & 15;
        int grow = min(r0 + row, N - 1);
        int slot = sub ^ (row & 7);
        *reinterpret_cast<uint4*>(reinterpret_cast<char*>(Al) + row * 256 + slot * 16) =
            *reinterpret_cast<const uint4*>(reinterpret_cast<const char*>(aggh) +
                                            (size_t)grow * 512 + sub * 16);
    }
    __syncthreads();

    int lane = tid & 63;
    int wave = tid >> 6;
    int wr = wave >> 1, wc = wave & 1;
    int lrow = lane & 15, hi = lane >> 4;

    f32x4 zero = {0.f, 0.f, 0.f, 0.f};
    f32x4 acc[4][4];
    #pragma unroll
    for (int rt = 0; rt < 4; ++rt)
        #pragma unroll
        for (int ct = 0; ct < 4; ++ct) acc[rt][ct] = zero;

    #pragma unroll
    for (int ks = 0; ks < 4; ++ks) {
        int chunk = ks * 4 + hi;
        bf16x8 af[4], bfr[4];
        #pragma unroll
        for (int rt = 0; rt < 4; ++rt) {
            int row = wr * 64 + rt * 16 + lrow;
            af[rt] = *reinterpret_cast<bf16x8*>(reinterpret_cast<char*>(Al) + row * 256 +
                                                ((chunk ^ (row & 7)) * 16));
        }
        #pragma unroll
        for (int ct = 0; ct < 4; ++ct) {
            int col = wc * 64 + ct * 16 + lrow;
            bfr[ct] = *reinterpret_cast<bf16x8*>(reinterpret_cast<char*>(Bl) + col * 256 +
                                                 ((chunk ^ (col & 7)) * 16));
        }
        #pragma unroll
        for (int rt = 0; rt < 4; ++rt)
            #pragma unroll
            for (int ct = 0; ct < 4; ++ct)
                acc[rt][ct] = __builtin_amdgcn_mfma_f32_16x16x32_bf16(af[rt], bfr[ct],
                                                                     acc[rt][ct], 0, 0, 0);
    }

    #pragma unroll
    for (int ct = 0; ct < 4; ++ct) {
        int col = wc * 64 + ct * 16 + lrow;
        float bias = b[col];
        #pragma unroll
        for (int rt = 0; rt < 4; ++rt) {
            int rbase = r0 + wr * 64 + rt * 16 + hi * 4;
            #pragma unroll
            for (int q = 0; q < 4; ++q) {
                int row = rbase + q;
                if (row < N) outp[(size_t)row * NFEAT + col] = acc[rt][ct][q] + bias;
            }
        }
    }
}

extern "C" void kernel_launch(void* const* d_in, const int* in_sizes, int n_in,
                              void* d_out, int out_size, void* d_ws, size_t ws_size,
                              hipStream_t stream) {
    const float* x   = (const float*)d_in[0];
    const int*   src = (const int*)d_in[1];
    const int*   dst = (const int*)d_in[2];
    const float* W   = (const float*)d_in[3];
    const float* b   = (const float*)d_in[4];

    const int N = in_sizes[0] / NFEAT;   // 100000
    const int E = in_sizes[1];           // 1600000
    float* out = (float*)d_out;

    const int NB = (N + BNODES - 1) >> BSHIFT;   // 196

    // ws layout (ints unless noted):
    // [out_deg N][cursor NBMAX]  <- zeroed together
    // [row_start N+1][inorm N f32][csr_src E][Wt 16384 bf16][xh N*128 bf16]
    int*   out_deg   = (int*)d_ws;
    int*   cursor    = out_deg + N;
    int*   row_start = cursor + NBMAX;
    float* inorm     = (float*)(row_start + (N + 1));
    int*   csr_src   = (int*)(inorm + N);
    u16*   Wt        = (u16*)(csr_src + E);
    u16*   xh        = Wt + NFEAT * NFEAT;

    // fixed-capacity packed buckets live in d_out (NB*BCAP ints = 7.2MB); dead before agg.
    int* packed = (int*)d_out;

    hipMemsetAsync(d_ws, 0, (size_t)(N + NBMAX) * sizeof(int), stream);

    int nchunk = (E + CHUNK - 1) / CHUNK;        // 391
    partition_kernel<<<nchunk, 512, 0, stream>>>(src, dst, E, cursor, packed, out_deg, NB);

    int nbc = (N + 127) >> 7;                    // 782 cast blocks
    fill_cast_kernel<<<NB + nbc + 1, 512, 0, stream>>>(packed, cursor,
                                                       row_start, inorm, csr_src,
                                                       x, out_deg, xh, W, Wt, N, E, NB, nbc);

    u16* aggh = (u16*)d_out;                     // strided: node i payload at byte i*512
    agg_bf16_kernel<<<(N + 7) / 8, 256, 0, stream>>>(xh, csr_src, row_start, inorm, aggh, N);

    mm_mfma_kernel<<<(N + 127) / 128, 256, 0, stream>>>(aggh, out, Wt, b, N);
}